// Round 1
// baseline (183.559 us; speedup 1.0000x reference)
//
#include <hip/hip_runtime.h>

#define TOKENS 9216
#define CDIM 256
#define NHEADS 8
#define HDIM 32
#define DD 4
#define HHH 48
#define WWW 48
#define QK_SCALE 0.17677669529663687f  // 32^-0.5

// ---------------- fp32 tiled GEMM: 128x128 tile, BK=16, 8x8 per thread ----------------
// mode 0: qkv epilogue  (N=768) -> split into o0=q(scaled),o1=k,o2=v laid out [head][token][32]
// mode 1: plain epilogue (o0[m*N+n] = acc + bias[n])
__global__ __launch_bounds__(256) void gemm_fp32(
    const float* __restrict__ A, const float* __restrict__ Bm,
    const float* __restrict__ bias, int N, int mode,
    float* __restrict__ o0, float* __restrict__ o1, float* __restrict__ o2)
{
    __shared__ float As[16][132];
    __shared__ float Bs[16][132];
    const int tid = threadIdx.x;
    const int m0 = blockIdx.y * 128;
    const int n0 = blockIdx.x * 128;
    const int tx = tid & 15, ty = tid >> 4;

    float acc[8][8];
    #pragma unroll
    for (int i = 0; i < 8; i++)
        #pragma unroll
        for (int j = 0; j < 8; j++) acc[i][j] = 0.f;

    for (int k0 = 0; k0 < 256; k0 += 16) {
        #pragma unroll
        for (int r = 0; r < 2; r++) {
            int idx = tid + 256 * r;
            int arow = idx >> 2, aq = idx & 3;
            float4 av = *(const float4*)(A + (size_t)(m0 + arow) * 256 + k0 + aq * 4);
            As[aq * 4 + 0][arow] = av.x;
            As[aq * 4 + 1][arow] = av.y;
            As[aq * 4 + 2][arow] = av.z;
            As[aq * 4 + 3][arow] = av.w;
            int brow = idx >> 5, bq = idx & 31;
            *(float4*)&Bs[brow][bq * 4] =
                *(const float4*)(Bm + (size_t)(k0 + brow) * N + n0 + bq * 4);
        }
        __syncthreads();
        #pragma unroll
        for (int kk = 0; kk < 16; kk++) {
            float a[8], b[8];
            *(float4*)&a[0] = *(const float4*)&As[kk][ty * 4];
            *(float4*)&a[4] = *(const float4*)&As[kk][64 + ty * 4];
            *(float4*)&b[0] = *(const float4*)&Bs[kk][tx * 4];
            *(float4*)&b[4] = *(const float4*)&Bs[kk][64 + tx * 4];
            #pragma unroll
            for (int i = 0; i < 8; i++)
                #pragma unroll
                for (int j = 0; j < 8; j++)
                    acc[i][j] = fmaf(a[i], b[j], acc[i][j]);
        }
        __syncthreads();
    }

    // epilogue
    #pragma unroll
    for (int rg = 0; rg < 2; rg++) {
        #pragma unroll
        for (int ii = 0; ii < 4; ii++) {
            int ai = rg * 4 + ii;
            int m = m0 + rg * 64 + ty * 4 + ii;
            #pragma unroll
            for (int cg = 0; cg < 2; cg++) {
                int n = n0 + cg * 64 + tx * 4;
                float4 bv = *(const float4*)(bias + n);
                float v0 = acc[ai][cg * 4 + 0] + bv.x;
                float v1 = acc[ai][cg * 4 + 1] + bv.y;
                float v2 = acc[ai][cg * 4 + 2] + bv.z;
                float v3 = acc[ai][cg * 4 + 3] + bv.w;
                if (mode == 0) {
                    int part = n >> 8;           // 0=q,1=k,2=v
                    int c    = n & 255;
                    int hh   = c >> 5;
                    int hd   = c & 31;
                    float* dst = (part == 0) ? o0 : ((part == 1) ? o1 : o2);
                    float sc = (part == 0) ? QK_SCALE : 1.f;
                    float4 v4 = make_float4(v0 * sc, v1 * sc, v2 * sc, v3 * sc);
                    *(float4*)(dst + ((size_t)hh * TOKENS + m) * HDIM + hd) = v4;
                } else {
                    float4 v4 = make_float4(v0, v1, v2, v3);
                    *(float4*)(o0 + (size_t)m * N + n) = v4;
                }
            }
        }
    }
}

// ---------------- neighborhood attention ----------------
// block: 1 head x (1 d, 4 y, 4 x) token tile; 256 threads = 4 waves; wave -> 4 tokens.
// LDS: union neighborhood K,V (3x8x8 = 192 vectors of 32), pad 33 for conflict-free
// per-lane row reads. Scores: lane j = neighbor j (and j+64 tail), 32-step dot.
__global__ __launch_bounds__(256) void nat_attn(
    const float* __restrict__ qws, const float* __restrict__ kws,
    const float* __restrict__ vws, const float* __restrict__ rpb,
    float* __restrict__ aout)
{
    __shared__ float Ks[192][33];
    __shared__ float Vs[192][33];
    __shared__ float ps[4][76];
    __shared__ int rowb[128];
    __shared__ int biasb[128];

    const int tid = threadIdx.x;
    int bid = blockIdx.x;
    const int h = bid & 7; bid >>= 3;
    const int bx = bid % 12; bid /= 12;
    const int by = bid % 12;
    const int d  = bid / 12;
    const int y0 = by * 4, x0 = bx * 4;
    const int base_d = min(max(d - 1, 0), DD - 3);    // window 3 in depth
    const int base_h = min(max(y0 - 2, 0), HHH - 8);  // window 8
    const int base_w = min(max(x0 - 2, 0), WWW - 8);  // window 8

    if (tid < 128) {
        int j = min(tid, 74);
        int jd = j / 25, r = j % 25, jh = r / 5, jw = r % 5;
        rowb[tid]  = jd * 64 + jh * 8 + jw;
        biasb[tid] = jd * 81 + jh * 9 + jw;
    }

    const float* kbase = kws + (size_t)h * TOKENS * HDIM;
    const float* vbase = vws + (size_t)h * TOKENS * HDIM;
    for (int idx = tid; idx < 192 * 8; idx += 256) {
        int row = idx >> 3, q4 = idx & 7;
        int ld = row >> 6, rem = row & 63, lh = rem >> 3, lw = rem & 7;
        int gt = ((base_d + ld) * HHH + (base_h + lh)) * WWW + (base_w + lw);
        float4 kv = *(const float4*)(kbase + (size_t)gt * HDIM + q4 * 4);
        float4 vv = *(const float4*)(vbase + (size_t)gt * HDIM + q4 * 4);
        Ks[row][q4 * 4 + 0] = kv.x; Ks[row][q4 * 4 + 1] = kv.y;
        Ks[row][q4 * 4 + 2] = kv.z; Ks[row][q4 * 4 + 3] = kv.w;
        Vs[row][q4 * 4 + 0] = vv.x; Vs[row][q4 * 4 + 1] = vv.y;
        Vs[row][q4 * 4 + 2] = vv.z; Vs[row][q4 * 4 + 3] = vv.w;
    }
    __syncthreads();

    const int w = tid >> 6, lane = tid & 63;
    const int half = lane >> 5, cc = lane & 31;
    const int j1 = lane + 64;
    const bool vj1 = (j1 < 75);
    const int rb0 = rowb[lane], bb0 = biasb[lane];
    const int rb1 = rowb[j1],  bb1 = biasb[j1];
    const float* rpbh = rpb + h * 405;  // 5*9*9
    const float* qbase = qws + (size_t)h * TOKENS * HDIM;

    for (int i = 0; i < 4; i++) {
        int t = w * 4 + i;
        int y = y0 + (t >> 2), x = x0 + (t & 3);
        int sh = min(max(y - 2, 0), HHH - 5);
        int sw = min(max(x - 2, 0), WWW - 5);
        int tokoff  = (sh - base_h) * 8 + (sw - base_w);
        int relbase = (base_d - d + 2) * 81 + (sh - y + 4) * 9 + (sw - x + 4);
        int gt = (d * HHH + y) * WWW + x;
        const float* qrow = qbase + (size_t)gt * HDIM;

        float4 qv[8];
        #pragma unroll
        for (int q = 0; q < 8; q++) qv[q] = ((const float4*)qrow)[q];

        int r0 = rb0 + tokoff, r1 = rb1 + tokoff;
        float d0 = 0.f, d1 = 0.f;
        #pragma unroll
        for (int c4 = 0; c4 < 8; c4++) {
            float4 q4v = qv[c4];
            d0 = fmaf(q4v.x, Ks[r0][c4 * 4 + 0], d0);
            d1 = fmaf(q4v.x, Ks[r1][c4 * 4 + 0], d1);
            d0 = fmaf(q4v.y, Ks[r0][c4 * 4 + 1], d0);
            d1 = fmaf(q4v.y, Ks[r1][c4 * 4 + 1], d1);
            d0 = fmaf(q4v.z, Ks[r0][c4 * 4 + 2], d0);
            d1 = fmaf(q4v.z, Ks[r1][c4 * 4 + 2], d1);
            d0 = fmaf(q4v.w, Ks[r0][c4 * 4 + 3], d0);
            d1 = fmaf(q4v.w, Ks[r1][c4 * 4 + 3], d1);
        }
        float s0 = d0 + rpbh[relbase + bb0];
        float s1 = vj1 ? (d1 + rpbh[relbase + bb1]) : -1e30f;

        float mx = fmaxf(s0, s1);
        #pragma unroll
        for (int off = 32; off >= 1; off >>= 1) mx = fmaxf(mx, __shfl_xor(mx, off));
        float e0 = __expf(s0 - mx);
        float e1 = vj1 ? __expf(s1 - mx) : 0.f;
        float sm = e0 + e1;
        #pragma unroll
        for (int off = 32; off >= 1; off >>= 1) sm += __shfl_xor(sm, off);
        float inv = 1.f / sm;
        ps[w][lane] = e0 * inv;
        if (vj1) ps[w][j1] = e1 * inv;

        // PV: lanes = channel dim, halves take even/odd neighbors
        float acc = 0.f;
        #pragma unroll
        for (int it = 0; it < 38; it++) {
            int j = it * 2 + half;
            if (j < 75) {
                float p = ps[w][j];
                int rv = rowb[j] + tokoff;
                acc = fmaf(p, Vs[rv][cc], acc);
            }
        }
        acc += __shfl_xor(acc, 32);
        if (half == 0)
            aout[(size_t)gt * CDIM + h * HDIM + cc] = acc;
    }
}

extern "C" void kernel_launch(void* const* d_in, const int* in_sizes, int n_in,
                              void* d_out, int out_size, void* d_ws, size_t ws_size,
                              hipStream_t stream) {
    const float* x      = (const float*)d_in[0];
    const float* w_qkv  = (const float*)d_in[1];
    const float* b_qkv  = (const float*)d_in[2];
    const float* rpb    = (const float*)d_in[3];
    const float* w_proj = (const float*)d_in[4];
    const float* b_proj = (const float*)d_in[5];
    float* out = (float*)d_out;

    float* ws  = (float*)d_ws;
    float* qws = ws;                       // [8][9216][32]
    float* kws = ws + (size_t)2359296;     // [8][9216][32]
    float* vws = ws + (size_t)4718592;     // [8][9216][32]
    float* aws = ws + (size_t)7077888;     // [9216][256]

    // QKV projection: x[9216,256] @ w_qkv[256,768]
    gemm_fp32<<<dim3(6, 72), 256, 0, stream>>>(x, w_qkv, b_qkv, 768, 0, qws, kws, vws);
    // neighborhood attention
    nat_attn<<<dim3(4608), 256, 0, stream>>>(qws, kws, vws, rpb, aws);
    // output projection: aws[9216,256] @ w_proj[256,256]
    gemm_fp32<<<dim3(2, 72), 256, 0, stream>>>(aws, w_proj, b_proj, 256, 1, out, nullptr, nullptr);
}

// Round 2
// 70.282 us; speedup vs baseline: 2.6117x; 2.6117x over previous
//
#include <hip/hip_runtime.h>

#define QK_SCALE 0.17677669529663687f  // 32^-0.5
#define TOKENS 9216

typedef __attribute__((ext_vector_type(8))) __bf16 bf16x8;
typedef __attribute__((ext_vector_type(8))) unsigned short us8;
typedef __attribute__((ext_vector_type(4))) float f32x4;

static __device__ __forceinline__ unsigned short f2bf(float x) {
    unsigned int u = __float_as_uint(x);
    return (unsigned short)((u + 0x7FFFu + ((u >> 16) & 1u)) >> 16);
}
static __device__ __forceinline__ bf16x8 ld_bf8(const unsigned short* p) {
    us8 u = *reinterpret_cast<const us8*>(p);
    return __builtin_bit_cast(bf16x8, u);
}

// ---------- prep: x -> bf16 ; w_qkv -> bf16 transposed [768][256]; w_proj -> bf16 T [256][256]
__global__ __launch_bounds__(256) void conv_prep(
    const float* __restrict__ x, const float* __restrict__ wqkv, const float* __restrict__ wproj,
    unsigned short* __restrict__ xb, unsigned short* __restrict__ wqT, unsigned short* __restrict__ wpT)
{
    int b = blockIdx.x, t = threadIdx.x;
    if (b < 2304) {
        int idx = (b * 256 + t) * 4;
        float4 v = *reinterpret_cast<const float4*>(x + idx);
        ushort4 o;
        o.x = f2bf(v.x); o.y = f2bf(v.y); o.z = f2bf(v.z); o.w = f2bf(v.w);
        *reinterpret_cast<ushort4*>(xb + idx) = o;
    } else if (b < 3072) {
        int e = (b - 2304) * 256 + t;      // 768*256
        int n = e >> 8, k = e & 255;
        wqT[n * 256 + k] = f2bf(wqkv[k * 768 + n]);
    } else {
        int e = (b - 3072) * 256 + t;      // 256*256
        int n = e >> 8, k = e & 255;
        wpT[n * 256 + k] = f2bf(wproj[k * 256 + n]);
    }
}

// ---------- LDS-free MFMA GEMM: C[M][N] = A[M][256] * BT[N][256]^T, K=256
// block = 4 waves in 2x2; wave tile = (MF*16) x (NF*16).
// MODE 0: qkv split epilogue -> q*SCALE,k,v bf16 [head][token][32]
// MODE 1: float out + bias
template<int MF, int NF, int MODE>
__global__ __launch_bounds__(256) void gemm_mfma(
    const unsigned short* __restrict__ A, const unsigned short* __restrict__ BT,
    const float* __restrict__ bias,
    unsigned short* __restrict__ oq, unsigned short* __restrict__ ok,
    unsigned short* __restrict__ ov, float* __restrict__ of)
{
    const int tid = threadIdx.x;
    const int wid = tid >> 6, lane = tid & 63;
    const int wm = wid >> 1, wn = wid & 1;
    const int n15 = lane & 15, g = lane >> 4;
    const int m0 = blockIdx.y * (MF * 32) + wm * (MF * 16);
    const int n0 = blockIdx.x * (NF * 32) + wn * (NF * 16);

    f32x4 acc[MF][NF];
    #pragma unroll
    for (int i = 0; i < MF; i++)
        #pragma unroll
        for (int j = 0; j < NF; j++)
            acc[i][j] = f32x4{0.f, 0.f, 0.f, 0.f};

    #pragma unroll
    for (int ks = 0; ks < 8; ++ks) {
        bf16x8 a[MF], b[NF];
        #pragma unroll
        for (int mt = 0; mt < MF; ++mt)
            a[mt] = ld_bf8(A + (size_t)(m0 + mt * 16 + n15) * 256 + ks * 32 + g * 8);
        #pragma unroll
        for (int nt = 0; nt < NF; ++nt)
            b[nt] = ld_bf8(BT + (size_t)(n0 + nt * 16 + n15) * 256 + ks * 32 + g * 8);
        #pragma unroll
        for (int mt = 0; mt < MF; ++mt)
            #pragma unroll
            for (int nt = 0; nt < NF; ++nt)
                acc[mt][nt] = __builtin_amdgcn_mfma_f32_16x16x32_bf16(a[mt], b[nt], acc[mt][nt], 0, 0, 0);
    }

    #pragma unroll
    for (int mt = 0; mt < MF; ++mt) {
        #pragma unroll
        for (int nt = 0; nt < NF; ++nt) {
            int col = n0 + nt * 16 + n15;
            float bv = bias[col];
            #pragma unroll
            for (int rg = 0; rg < 4; ++rg) {
                int row = m0 + mt * 16 + g * 4 + rg;
                float val = acc[mt][nt][rg] + bv;
                if (MODE == 0) {
                    int part = col >> 8, c = col & 255, hh = c >> 5, ch = c & 31;
                    unsigned short* dst = (part == 0) ? oq : ((part == 1) ? ok : ov);
                    if (part == 0) val *= QK_SCALE;
                    dst[((size_t)hh * TOKENS + row) * 32 + ch] = f2bf(val);
                } else {
                    of[(size_t)row * 256 + col] = val;
                }
            }
        }
    }
}

// ---------- MFMA neighborhood attention ----------
// block: 1 head x 4x4x1 token tile (16 tokens), candidate union = 3x8x8 = 192.
// 2 waves: wave w owns score tiles (cands 96w..96w+95) and PV n-tile w (channels 16w..16w+15).
__global__ __launch_bounds__(128) void nat_attn_mfma(
    const unsigned short* __restrict__ qws, const unsigned short* __restrict__ kws,
    const unsigned short* __restrict__ vws, const float* __restrict__ rpb,
    unsigned short* __restrict__ aout)
{
    __shared__ unsigned short VT[32 * 200];   // V^T [ch][cand], stride 200 (400B, 16B-aligned)
    __shared__ unsigned short Pl[16 * 200];   // P   [tok][cand]
    __shared__ float biasL[405];
    __shared__ float red[2][16][2];

    const int tid = threadIdx.x;
    const int w = tid >> 6, lane = tid & 63;
    const int n15 = lane & 15, g = lane >> 4;

    int b = blockIdx.x;
    const int h = b & 7; b >>= 3;
    const int bx = b % 12; b /= 12;
    const int by = b % 12;
    const int d  = b / 12;
    const int y0 = by * 4, x0 = bx * 4;
    const int base_d = min(max(d - 1, 0), 1);
    const int base_h = min(max(y0 - 2, 0), 40);
    const int base_w = min(max(x0 - 2, 0), 40);
    const int relD = base_d - d + 2;

    const size_t hoff = (size_t)h * TOKENS * 32;
    const unsigned short* kb = kws + hoff;
    const unsigned short* vb = vws + hoff;
    const unsigned short* qb = qws + hoff;

    for (int i = tid; i < 405; i += 128) biasL[i] = rpb[h * 405 + i];

    for (int id = tid; id < 768; id += 128) {
        int cand = id % 192, chg = id / 192;
        int ld = cand >> 6, lh = (cand >> 3) & 7, lw = cand & 7;
        int gt = (base_d + ld) * 2304 + (base_h + lh) * 48 + (base_w + lw);
        us8 u = *reinterpret_cast<const us8*>(vb + (size_t)gt * 32 + chg * 8);
        #pragma unroll
        for (int e = 0; e < 8; e++) VT[(chg * 8 + e) * 200 + cand] = u[e];
    }
    __syncthreads();

    // ---- QK^T ----
    const int gtq = d * 2304 + (y0 + (n15 >> 2)) * 48 + (x0 + (n15 & 3));
    bf16x8 qf = ld_bf8(qb + (size_t)gtq * 32 + g * 8);

    f32x4 sf[6];
    #pragma unroll
    for (int i = 0; i < 6; ++i) {
        int cand = (w * 6 + i) * 16 + n15;
        int ld = cand >> 6, lh = (cand >> 3) & 7, lw = cand & 7;
        int gtc = (base_d + ld) * 2304 + (base_h + lh) * 48 + (base_w + lw);
        bf16x8 kf = ld_bf8(kb + (size_t)gtc * 32 + g * 8);
        sf[i] = __builtin_amdgcn_mfma_f32_16x16x32_bf16(qf, kf, f32x4{0.f, 0.f, 0.f, 0.f}, 0, 0, 0);
    }

    // per-reg token geometry
    int shl[4], swl[4], oy[4], ox[4], gtr[4];
    #pragma unroll
    for (int rg = 0; rg < 4; ++rg) {
        int tok = g * 4 + rg;
        int y = y0 + (tok >> 2), x = x0 + (tok & 3);
        int sh = min(max(y - 2, 0), 43), sw = min(max(x - 2, 0), 43);
        shl[rg] = sh - base_h; swl[rg] = sw - base_w;
        oy[rg] = y - base_h;   ox[rg] = x - base_w;
        gtr[rg] = d * 2304 + y * 48 + x;
    }

    float ev[6][4], mw[4], sm[4];
    #pragma unroll
    for (int rg = 0; rg < 4; ++rg) {
        float mx = -1e30f;
        #pragma unroll
        for (int i = 0; i < 6; ++i) {
            int cand = (w * 6 + i) * 16 + n15;
            int ld = cand >> 6, lh = (cand >> 3) & 7, lw = cand & 7;
            int t0 = lh - shl[rg], t1 = lw - swl[rg];
            bool valid = ((unsigned)t0 < 5u) && ((unsigned)t1 < 5u);
            int bi = (relD + ld) * 81 + (lh - oy[rg] + 4) * 9 + (lw - ox[rg] + 4);
            float bvv = biasL[valid ? bi : 0];
            float sc = valid ? (sf[i][rg] + bvv) : -1e30f;
            ev[i][rg] = sc;
            mx = fmaxf(mx, sc);
        }
        #pragma unroll
        for (int msk = 1; msk < 16; msk <<= 1) mx = fmaxf(mx, __shfl_xor(mx, msk));
        float ssum = 0.f;
        #pragma unroll
        for (int i = 0; i < 6; ++i) {
            float ee = __expf(ev[i][rg] - mx);
            ev[i][rg] = ee;
            ssum += ee;
        }
        #pragma unroll
        for (int msk = 1; msk < 16; msk <<= 1) ssum += __shfl_xor(ssum, msk);
        mw[rg] = mx; sm[rg] = ssum;
    }
    if (n15 == 0) {
        #pragma unroll
        for (int rg = 0; rg < 4; ++rg) {
            red[w][g * 4 + rg][0] = mw[rg];
            red[w][g * 4 + rg][1] = sm[rg];
        }
    }
    __syncthreads();

    float fac[4];
    #pragma unroll
    for (int rg = 0; rg < 4; ++rg) {
        int tk = g * 4 + rg;
        float m0_ = red[0][tk][0], s0_ = red[0][tk][1];
        float m1_ = red[1][tk][0], s1_ = red[1][tk][1];
        float m = fmaxf(m0_, m1_);
        float tot = s0_ * __expf(m0_ - m) + s1_ * __expf(m1_ - m);
        fac[rg] = __expf(mw[rg] - m) / tot;
    }
    #pragma unroll
    for (int rg = 0; rg < 4; ++rg)
        #pragma unroll
        for (int i = 0; i < 6; ++i)
            Pl[(g * 4 + rg) * 200 + (w * 6 + i) * 16 + n15] = f2bf(ev[i][rg] * fac[rg]);
    __syncthreads();

    // ---- PV ----
    f32x4 oacc = f32x4{0.f, 0.f, 0.f, 0.f};
    #pragma unroll
    for (int ks = 0; ks < 6; ++ks) {
        bf16x8 pa = ld_bf8(&Pl[n15 * 200 + ks * 32 + g * 8]);
        bf16x8 vf = ld_bf8(&VT[(w * 16 + n15) * 200 + ks * 32 + g * 8]);
        oacc = __builtin_amdgcn_mfma_f32_16x16x32_bf16(pa, vf, oacc, 0, 0, 0);
    }
    #pragma unroll
    for (int rg = 0; rg < 4; ++rg)
        aout[(size_t)gtr[rg] * 256 + h * 32 + w * 16 + n15] = f2bf(oacc[rg]);
}

extern "C" void kernel_launch(void* const* d_in, const int* in_sizes, int n_in,
                              void* d_out, int out_size, void* d_ws, size_t ws_size,
                              hipStream_t stream) {
    const float* x      = (const float*)d_in[0];
    const float* w_qkv  = (const float*)d_in[1];
    const float* b_qkv  = (const float*)d_in[2];
    const float* rpb    = (const float*)d_in[3];
    const float* w_proj = (const float*)d_in[4];
    const float* b_proj = (const float*)d_in[5];
    float* out = (float*)d_out;

    unsigned short* ws = (unsigned short*)d_ws;
    unsigned short* xb    = ws;                       // 2359296
    unsigned short* wqT   = ws + (size_t)2359296;     // 196608
    unsigned short* wpT   = ws + (size_t)2555904;     // 65536
    unsigned short* qws   = ws + (size_t)2621440;     // 2359296
    unsigned short* kws   = ws + (size_t)4980736;     // 2359296
    unsigned short* vws   = ws + (size_t)7340032;     // 2359296
    unsigned short* aws   = ws + (size_t)9699328;     // 2359296

    conv_prep<<<dim3(3328), 256, 0, stream>>>(x, w_qkv, w_proj, xb, wqT, wpT);

    // QKV: [9216,256] x [256,768] ; BM=128, BN=128
    gemm_mfma<4, 4, 0><<<dim3(6, 72), 256, 0, stream>>>(xb, wqT, b_qkv, qws, kws, vws, nullptr);

    nat_attn_mfma<<<dim3(4608), 128, 0, stream>>>(qws, kws, vws, rpb, aws);

    // proj: [9216,256] x [256,256] ; BM=64, BN=64
    gemm_mfma<2, 2, 1><<<dim3(4, 144), 256, 0, stream>>>(aws, wpT, b_proj, nullptr, nullptr, nullptr, out);
}